// Round 3
// baseline (4334.553 us; speedup 1.0000x reference)
//
#include <hip/hip_runtime.h>
#include <hip/hip_bf16.h>
#include <stdint.h>

// MoTEmbed: out[t,:] = W_{type(t)} @ h[t,:] + b_{type(t)}
// B=4, S=4096 -> T=16384 tokens, D=2048. fp32 in/out.
// Round 3: DIAGNOSTIC — pure fp32 vector-ALU tiled GEMM, same indexing
// conventions as the MFMA kernel but no MFMA / no bf16 / no fragment maps.
// Isolates whether the persistent absmax=5.6 failure is in problem semantics
// (would fail here too) or in the MFMA/bf16 machinery (would pass here).

#define T_TOK 16384
#define DDIM  2048
#define BMd   64
#define BNd   64
#define BKd   32
#define LDW   36   // padded f32 row stride: 144B, 16B-aligned for f32x4 stores

typedef __attribute__((ext_vector_type(4))) float f32x4;

__global__ __launch_bounds__(256, 2) void mot_diag_f32(
    const float* __restrict__ H,  const int* __restrict__ TYP,
    const float* __restrict__ W0, const float* __restrict__ B0,
    const float* __restrict__ W1, const float* __restrict__ B1,
    float* __restrict__ OUT)
{
  __shared__ float As[BMd * LDW];
  __shared__ float W0s[BNd * LDW];
  __shared__ float W1s[BNd * LDW];

  const int tid = threadIdx.x;
  const int bx = blockIdx.x;            // N tile (0..31)
  const int by = blockIdx.y;            // M tile (0..255)
  const int rowBase = by * BMd;
  const int colBase = bx * BNd;

  // staging: 256 threads cover 64x32 f32 tile in 2 passes
  const int srow  = tid >> 3;           // 0..31
  const int scol4 = (tid & 7) << 2;     // 0,4,...,28
  const float* hA  = H  + (size_t)(rowBase + srow) * DDIM + scol4;
  const float* hW0 = W0 + (size_t)(colBase + srow) * DDIM + scol4;
  const float* hW1 = W1 + (size_t)(colBase + srow) * DDIM + scol4;

  // compute mapping: 16x16 thread grid, each thread 4x4 outputs
  const int tx = tid & 15;
  const int ty = tid >> 4;

  float acc0[4][4], acc1[4][4];
#pragma unroll
  for (int i = 0; i < 4; ++i)
#pragma unroll
    for (int j = 0; j < 4; ++j) { acc0[i][j] = 0.0f; acc1[i][j] = 0.0f; }

  for (int k0 = 0; k0 < DDIM; k0 += BKd) {
    f32x4 va[2], v0[2], v1[2];
#pragma unroll
    for (int p = 0; p < 2; ++p) {
      va[p] = *(const f32x4*)(hA  + (size_t)p * 32 * DDIM);
      v0[p] = *(const f32x4*)(hW0 + (size_t)p * 32 * DDIM);
      v1[p] = *(const f32x4*)(hW1 + (size_t)p * 32 * DDIM);
    }
    hA += BKd; hW0 += BKd; hW1 += BKd;

    __syncthreads();   // previous iteration's readers done
#pragma unroll
    for (int p = 0; p < 2; ++p) {
      int r = srow + 32 * p;
      *(f32x4*)(&As [r * LDW + scol4]) = va[p];
      *(f32x4*)(&W0s[r * LDW + scol4]) = v0[p];
      *(f32x4*)(&W1s[r * LDW + scol4]) = v1[p];
    }
    __syncthreads();

#pragma unroll 8
    for (int kk = 0; kk < BKd; ++kk) {
      float a[4], w0v[4], w1v[4];
#pragma unroll
      for (int i = 0; i < 4; ++i) a[i]   = As [(ty * 4 + i) * LDW + kk];
#pragma unroll
      for (int j = 0; j < 4; ++j) w0v[j] = W0s[(tx * 4 + j) * LDW + kk];
#pragma unroll
      for (int j = 0; j < 4; ++j) w1v[j] = W1s[(tx * 4 + j) * LDW + kk];
#pragma unroll
      for (int i = 0; i < 4; ++i)
#pragma unroll
        for (int j = 0; j < 4; ++j) {
          acc0[i][j] = fmaf(a[i], w0v[j], acc0[i][j]);
          acc1[i][j] = fmaf(a[i], w1v[j], acc1[i][j]);
        }
    }
  }

  // epilogue: expert select per token + bias
#pragma unroll
  for (int i = 0; i < 4; ++i) {
    int row = rowBase + ty * 4 + i;
    int t = TYP[row];
    float* op = OUT + (size_t)row * DDIM;
#pragma unroll
    for (int j = 0; j < 4; ++j) {
      int col = colBase + tx * 4 + j;
      float v = (t == 0) ? (acc0[i][j] + B0[col]) : (acc1[i][j] + B1[col]);
      op[col] = v;
    }
  }
}

extern "C" void kernel_launch(void* const* d_in, const int* in_sizes, int n_in,
                              void* d_out, int out_size, void* d_ws, size_t ws_size,
                              hipStream_t stream) {
  const float* H   = (const float*)d_in[0];
  const int*   TYP = (const int*)  d_in[1];
  const float* W0  = (const float*)d_in[2];
  const float* B0v = (const float*)d_in[3];
  const float* W1  = (const float*)d_in[4];
  const float* B1v = (const float*)d_in[5];
  float* OUT = (float*)d_out;

  dim3 grid(DDIM / BNd, T_TOK / BMd);   // (32, 256)
  mot_diag_f32<<<grid, dim3(256), 0, stream>>>(H, TYP, W0, B0v, W1, B1v, OUT);
}

// Round 4
// 780.017 us; speedup vs baseline: 5.5570x; 5.5570x over previous
//
#include <hip/hip_runtime.h>
#include <hip/hip_bf16.h>
#include <stdint.h>

// MoTEmbed: out[t,:] = W_{type(t)} @ h[t,:] + b_{type(t)}
// B=4, S=4096 -> T=16384 tokens, D=2048. fp32 in/out.
// Round 4: DIFFERENTIAL — identical to the PASSING round-3 kernel (same grid,
// same f32 LDS staging, same epilogue logic) except the inner product is
// mfma_f32_16x16x32_bf16 with fp32->bf16 conversion at fragment-load time.
// Isolates MFMA usage from the bf16 LDS-staging path of rounds 1-2.

#define T_TOK 16384
#define DDIM  2048
#define BMd   64
#define BNd   64
#define BKd   32
#define LDW   36   // padded f32 row stride (144B)

typedef __attribute__((ext_vector_type(4))) float          f32x4;
typedef __attribute__((ext_vector_type(8))) short          bf16x8;

__device__ __forceinline__ unsigned short cvt1_bf16(float f) {
  unsigned u = __builtin_bit_cast(unsigned, f);
  unsigned rnd = 0x7fffu + ((u >> 16) & 1u);
  return (unsigned short)((u + rnd) >> 16);
}

__device__ __forceinline__ bf16x8 cvt_bf16x8(f32x4 lo, f32x4 hi) {
  bf16x8 r;
#pragma unroll
  for (int i = 0; i < 4; ++i) {
    r[i]     = (short)cvt1_bf16(lo[i]);
    r[i + 4] = (short)cvt1_bf16(hi[i]);
  }
  return r;
}

__global__ __launch_bounds__(256, 2) void mot_mfma_diag(
    const float* __restrict__ H,  const int* __restrict__ TYP,
    const float* __restrict__ W0, const float* __restrict__ B0,
    const float* __restrict__ W1, const float* __restrict__ B1,
    float* __restrict__ OUT)
{
  __shared__ float As[BMd * LDW];
  __shared__ float W0s[BNd * LDW];
  __shared__ float W1s[BNd * LDW];

  const int tid = threadIdx.x;
  const int bx = blockIdx.x;            // N tile (0..31)
  const int by = blockIdx.y;            // M tile (0..255)
  const int rowBase = by * BMd;
  const int colBase = bx * BNd;

  // staging: identical to round-3 (PASSING) kernel
  const int srow  = tid >> 3;           // 0..31
  const int scol4 = (tid & 7) << 2;     // 0,4,...,28
  const float* hA  = H  + (size_t)(rowBase + srow) * DDIM + scol4;
  const float* hW0 = W0 + (size_t)(colBase + srow) * DDIM + scol4;
  const float* hW1 = W1 + (size_t)(colBase + srow) * DDIM + scol4;

  // wave decomposition: wave w owns cols [w*16, w*16+16), all 64 rows
  const int lane = tid & 63;
  const int w    = tid >> 6;            // 0..3
  const int fr   = lane & 15;
  const int g    = lane >> 4;           // k-group (8 floats)

  f32x4 acc0[4], acc1[4];               // 4 M-fragments x 2 experts
#pragma unroll
  for (int m = 0; m < 4; ++m) { acc0[m] = (f32x4)0.0f; acc1[m] = (f32x4)0.0f; }

  for (int k0 = 0; k0 < DDIM; k0 += BKd) {
    f32x4 va[2], v0[2], v1[2];
#pragma unroll
    for (int p = 0; p < 2; ++p) {
      va[p] = *(const f32x4*)(hA  + (size_t)p * 32 * DDIM);
      v0[p] = *(const f32x4*)(hW0 + (size_t)p * 32 * DDIM);
      v1[p] = *(const f32x4*)(hW1 + (size_t)p * 32 * DDIM);
    }
    hA += BKd; hW0 += BKd; hW1 += BKd;

    __syncthreads();
#pragma unroll
    for (int p = 0; p < 2; ++p) {
      int r = srow + 32 * p;
      *(f32x4*)(&As [r * LDW + scol4]) = va[p];
      *(f32x4*)(&W0s[r * LDW + scol4]) = v0[p];
      *(f32x4*)(&W1s[r * LDW + scol4]) = v1[p];
    }
    __syncthreads();

    // fragments from f32 LDS, converted in registers
    bf16x8 af[4];
#pragma unroll
    for (int m = 0; m < 4; ++m) {
      const float* ap = &As[(m * 16 + fr) * LDW + g * 8];
      af[m] = cvt_bf16x8(*(const f32x4*)ap, *(const f32x4*)(ap + 4));
    }
    const float* b0p = &W0s[(w * 16 + fr) * LDW + g * 8];
    const float* b1p = &W1s[(w * 16 + fr) * LDW + g * 8];
    bf16x8 bf0 = cvt_bf16x8(*(const f32x4*)b0p, *(const f32x4*)(b0p + 4));
    bf16x8 bf1 = cvt_bf16x8(*(const f32x4*)b1p, *(const f32x4*)(b1p + 4));

#pragma unroll
    for (int m = 0; m < 4; ++m) {
      acc0[m] = __builtin_amdgcn_mfma_f32_16x16x32_bf16(af[m], bf0, acc0[m], 0, 0, 0);
      acc1[m] = __builtin_amdgcn_mfma_f32_16x16x32_bf16(af[m], bf1, acc1[m], 0, 0, 0);
    }
  }

  // epilogue: same select/bias logic as round-3; C/D map col=lane&15,
  // row=(lane>>4)*4+j (m89)
  const int col = colBase + w * 16 + fr;
  const float bz0 = B0[col];
  const float bz1 = B1[col];
#pragma unroll
  for (int m = 0; m < 4; ++m) {
#pragma unroll
    for (int j = 0; j < 4; ++j) {
      int row = rowBase + m * 16 + (g << 2) + j;
      int t = TYP[row];
      float v = (t == 0) ? (acc0[m][j] + bz0) : (acc1[m][j] + bz1);
      OUT[(size_t)row * DDIM + col] = v;
    }
  }
}

extern "C" void kernel_launch(void* const* d_in, const int* in_sizes, int n_in,
                              void* d_out, int out_size, void* d_ws, size_t ws_size,
                              hipStream_t stream) {
  const float* H   = (const float*)d_in[0];
  const int*   TYP = (const int*)  d_in[1];
  const float* W0  = (const float*)d_in[2];
  const float* B0v = (const float*)d_in[3];
  const float* W1  = (const float*)d_in[4];
  const float* B1v = (const float*)d_in[5];
  float* OUT = (float*)d_out;

  dim3 grid(DDIM / BNd, T_TOK / BMd);   // (32, 256)
  mot_mfma_diag<<<grid, dim3(256), 0, stream>>>(H, TYP, W0, B0v, W1, B1v, OUT);
}

// Round 5
// 256.153 us; speedup vs baseline: 16.9217x; 3.0451x over previous
//
#include <hip/hip_runtime.h>
#include <hip/hip_bf16.h>
#include <stdint.h>

// MoTEmbed: out[t,:] = W_{type(t)} @ h[t,:] + b_{type(t)}
// B=4, S=4096 -> T=16384 tokens, D=2048. fp32 in/out, bf16 MFMA compute.
// Round 5: token-sort by type (single-expert GEMM, halves FLOPs) +
// pre-converted bf16 operands in d_ws + m97-structure global_load_lds GEMM.
// Falls back to the verified round-4 kernel if ws_size < 84 MB.

#define T_TOK 16384
#define DDIM  2048
#define NTILE 16         // N tiles of 128
#define MTILE 129        // 128 + 1 (padding split worst case)

typedef __attribute__((ext_vector_type(4))) float          f32x4;
typedef __attribute__((ext_vector_type(8))) short          bf16x8;
typedef __attribute__((ext_vector_type(2))) unsigned int   u32x2;

// ---- ws layout (bytes) ----
#define WS_HBF   0ull
#define WS_W0BF  67108864ull                 // 16384*2048*2
#define WS_W1BF  75497472ull                 // + 2048*2048*2
#define WS_META  83886080ull                 // + 2048*2048*2
#define WS_IDX   83886208ull                 // meta padded to 128B
#define WS_NEED  (WS_IDX + (unsigned long long)(T_TOK + 256) * 4ull)
// meta: [0]=c0 [1]=c0pad [2]=cur0 [3]=cur1

__device__ __forceinline__ unsigned short cvt1_bf16(float f) {
  unsigned u = __builtin_bit_cast(unsigned, f);
  unsigned rnd = 0x7fffu + ((u >> 16) & 1u);
  return (unsigned short)((u + rnd) >> 16);
}

__device__ __forceinline__ void gload_lds16(const void* g, void* l) {
  __builtin_amdgcn_global_load_lds(
      (const __attribute__((address_space(1))) unsigned int*)g,
      (__attribute__((address_space(3))) unsigned int*)l, 16, 0, 0);
}

// ---------- prep kernels ----------
__global__ void k_convert(const float* __restrict__ src,
                          unsigned short* __restrict__ dst, int n4) {
  int i = blockIdx.x * blockDim.x + threadIdx.x;
  int stride = gridDim.x * blockDim.x;
  for (; i < n4; i += stride) {
    f32x4 v = ((const f32x4*)src)[i];
    unsigned p0 = (unsigned)cvt1_bf16(v[0]) | ((unsigned)cvt1_bf16(v[1]) << 16);
    unsigned p1 = (unsigned)cvt1_bf16(v[2]) | ((unsigned)cvt1_bf16(v[3]) << 16);
    u32x2 o; o[0] = p0; o[1] = p1;
    ((u32x2*)dst)[i] = o;
  }
}

__global__ void k_init(int* __restrict__ meta, int* __restrict__ idx, int n) {
  int i = blockIdx.x * blockDim.x + threadIdx.x;
  if (i < 4) meta[i] = 0;
  if (i < n) idx[i] = -1;
}

__global__ void k_count(const int* __restrict__ typ, int* __restrict__ meta) {
  int i = blockIdx.x * blockDim.x + threadIdx.x;
  if (i < T_TOK && typ[i] == 0) atomicAdd(&meta[0], 1);
}

__global__ void k_pad(int* __restrict__ meta) {
  meta[1] = ((meta[0] + 127) >> 7) << 7;
}

__global__ void k_scatter(const int* __restrict__ typ, int* __restrict__ meta,
                          int* __restrict__ idx) {
  int i = blockIdx.x * blockDim.x + threadIdx.x;
  if (i >= T_TOK) return;
  int t = typ[i];
  int pos;
  if (t == 0) pos = atomicAdd(&meta[2], 1);
  else        pos = meta[1] + atomicAdd(&meta[3], 1);
  idx[pos] = i;
}

// ---------- main GEMM (m97 structure, gathered A rows) ----------
__global__ __launch_bounds__(256, 2) void k_gemm(
    const unsigned short* __restrict__ Hbf,
    const unsigned short* __restrict__ W0bf,
    const unsigned short* __restrict__ W1bf,
    const float* __restrict__ B0, const float* __restrict__ B1,
    const int* __restrict__ meta, const int* __restrict__ idx,
    float* __restrict__ OUT)
{
  __shared__ char lds[16384];          // A 8KB | W 8KB, rows of 64B (32 bf16)
  char* Asm = lds;
  char* Wsm = lds + 8192;

  // bijective XCD swizzle (m204): nwg=2064, q=258
  const int orig = blockIdx.x;
  const int wg = (orig & 7) * 258 + (orig >> 3);
  const int my = wg >> 4;              // 0..128
  const int bx = wg & 15;              // 0..15

  const int tid  = threadIdx.x;
  const int lane = tid & 63;
  const int w    = tid >> 6;
  const int start   = my * 128;
  const int c0pad   = meta[1];
  const int expert  = (start >= c0pad) ? 1 : 0;
  const unsigned short* Wb = expert ? W1bf : W0bf;
  const int colBase = bx * 128;

  // staging: 16 chunks of 1KB (A:8, W:8); wave w owns A{2w,2w+1}, W{2w,2w+1}
  // chunk ch covers tile rows 16ch+(lane>>2); lane stages 16B at (lane&3)*16
  const unsigned short* aSrc[2];
  const unsigned short* wSrc[2];
  char* aDst[2];
  char* wDst[2];
#pragma unroll
  for (int c = 0; c < 2; ++c) {
    int ch = 2 * w + c;
    int trow = 16 * ch + (lane >> 2);
    int r = idx[start + trow];
    if (r < 0) r = 0;
    aSrc[c] = Hbf + (size_t)r * DDIM + (lane & 3) * 8;
    wSrc[c] = Wb  + (size_t)(colBase + trow) * DDIM + (lane & 3) * 8;
    aDst[c] = Asm + ch * 1024;
    wDst[c] = Wsm + ch * 1024;
  }

  // MFMA fragment mapping (R4-verified conventions)
  const int wr = w >> 1, wc = w & 1;   // 2x2 waves, each 64x64 out
  const int fr = lane & 15;
  const int g  = lane >> 4;
  int aoff[4], boff[4];
#pragma unroll
  for (int m = 0; m < 4; ++m) aoff[m] = (wr * 64 + m * 16 + fr) * 64 + g * 16;
#pragma unroll
  for (int n = 0; n < 4; ++n) boff[n] = (wc * 64 + n * 16 + fr) * 64 + g * 16;

  f32x4 acc[4][4];
#pragma unroll
  for (int m = 0; m < 4; ++m)
#pragma unroll
    for (int n = 0; n < 4; ++n) acc[m][n] = (f32x4)0.0f;

  for (int k0 = 0; k0 < DDIM; k0 += 32) {
#pragma unroll
    for (int c = 0; c < 2; ++c) {
      gload_lds16(aSrc[c], aDst[c]);
      gload_lds16(wSrc[c], wDst[c]);
      aSrc[c] += 32;
      wSrc[c] += 32;
    }
    __syncthreads();                   // drains vmcnt; all waves' tiles ready

    bf16x8 af[4], wf[4];
#pragma unroll
    for (int m = 0; m < 4; ++m) af[m] = *(const bf16x8*)(Asm + aoff[m]);
#pragma unroll
    for (int n = 0; n < 4; ++n) wf[n] = *(const bf16x8*)(Wsm + boff[n]);
#pragma unroll
    for (int n = 0; n < 4; ++n)
#pragma unroll
      for (int m = 0; m < 4; ++m)
        acc[m][n] = __builtin_amdgcn_mfma_f32_16x16x32_bf16(af[m], wf[n], acc[m][n], 0, 0, 0);

    __syncthreads();                   // readers done before next overwrite
  }

  // epilogue: bias + scatter to original rows (skip pad rows)
  const float* Bv = expert ? B1 : B0;
  float bias[4];
  int cols[4];
#pragma unroll
  for (int n = 0; n < 4; ++n) {
    cols[n] = colBase + wc * 64 + n * 16 + fr;
    bias[n] = Bv[cols[n]];
  }
#pragma unroll
  for (int m = 0; m < 4; ++m) {
    int lbase = wr * 64 + m * 16 + (g << 2);
#pragma unroll
    for (int j = 0; j < 4; ++j) {
      int orow = idx[start + lbase + j];
      if (orow < 0) continue;
      float* op = OUT + (size_t)orow * DDIM;
#pragma unroll
      for (int n = 0; n < 4; ++n) op[cols[n]] = acc[m][n][j] + bias[n];
    }
  }
}

// ---------- fallback: verified round-4 kernel ----------
#define BMd 64
#define BNd 64
#define BKd 32
#define LDW 36

__device__ __forceinline__ bf16x8 cvt_bf16x8(f32x4 lo, f32x4 hi) {
  bf16x8 r;
#pragma unroll
  for (int i = 0; i < 4; ++i) {
    r[i]     = (short)cvt1_bf16(lo[i]);
    r[i + 4] = (short)cvt1_bf16(hi[i]);
  }
  return r;
}

__global__ __launch_bounds__(256, 2) void mot_mfma_diag(
    const float* __restrict__ H,  const int* __restrict__ TYP,
    const float* __restrict__ W0, const float* __restrict__ B0,
    const float* __restrict__ W1, const float* __restrict__ B1,
    float* __restrict__ OUT)
{
  __shared__ float As[BMd * LDW];
  __shared__ float W0s[BNd * LDW];
  __shared__ float W1s[BNd * LDW];

  const int tid = threadIdx.x;
  const int rowBase = blockIdx.y * BMd;
  const int colBase = blockIdx.x * BNd;
  const int srow  = tid >> 3;
  const int scol4 = (tid & 7) << 2;
  const float* hA  = H  + (size_t)(rowBase + srow) * DDIM + scol4;
  const float* hW0 = W0 + (size_t)(colBase + srow) * DDIM + scol4;
  const float* hW1 = W1 + (size_t)(colBase + srow) * DDIM + scol4;

  const int lane = tid & 63;
  const int w    = tid >> 6;
  const int fr   = lane & 15;
  const int g    = lane >> 4;

  f32x4 acc0[4], acc1[4];
#pragma unroll
  for (int m = 0; m < 4; ++m) { acc0[m] = (f32x4)0.0f; acc1[m] = (f32x4)0.0f; }

  for (int k0 = 0; k0 < DDIM; k0 += BKd) {
    f32x4 va[2], v0[2], v1[2];
#pragma unroll
    for (int p = 0; p < 2; ++p) {
      va[p] = *(const f32x4*)(hA  + (size_t)p * 32 * DDIM);
      v0[p] = *(const f32x4*)(hW0 + (size_t)p * 32 * DDIM);
      v1[p] = *(const f32x4*)(hW1 + (size_t)p * 32 * DDIM);
    }
    hA += BKd; hW0 += BKd; hW1 += BKd;
    __syncthreads();
#pragma unroll
    for (int p = 0; p < 2; ++p) {
      int r = srow + 32 * p;
      *(f32x4*)(&As [r * LDW + scol4]) = va[p];
      *(f32x4*)(&W0s[r * LDW + scol4]) = v0[p];
      *(f32x4*)(&W1s[r * LDW + scol4]) = v1[p];
    }
    __syncthreads();

    bf16x8 af[4];
#pragma unroll
    for (int m = 0; m < 4; ++m) {
      const float* ap = &As[(m * 16 + fr) * LDW + g * 8];
      af[m] = cvt_bf16x8(*(const f32x4*)ap, *(const f32x4*)(ap + 4));
    }
    const float* b0p = &W0s[(w * 16 + fr) * LDW + g * 8];
    const float* b1p = &W1s[(w * 16 + fr) * LDW + g * 8];
    bf16x8 bf0 = cvt_bf16x8(*(const f32x4*)b0p, *(const f32x4*)(b0p + 4));
    bf16x8 bf1 = cvt_bf16x8(*(const f32x4*)b1p, *(const f32x4*)(b1p + 4));
#pragma unroll
    for (int m = 0; m < 4; ++m) {
      acc0[m] = __builtin_amdgcn_mfma_f32_16x16x32_bf16(af[m], bf0, acc0[m], 0, 0, 0);
      acc1[m] = __builtin_amdgcn_mfma_f32_16x16x32_bf16(af[m], bf1, acc1[m], 0, 0, 0);
    }
  }

  const int col = colBase + w * 16 + fr;
  const float bz0 = B0[col];
  const float bz1 = B1[col];
#pragma unroll
  for (int m = 0; m < 4; ++m)
#pragma unroll
    for (int j = 0; j < 4; ++j) {
      int row = rowBase + m * 16 + (g << 2) + j;
      int t = TYP[row];
      OUT[(size_t)row * DDIM + col] = (t == 0) ? (acc0[m][j] + bz0) : (acc1[m][j] + bz1);
    }
}

extern "C" void kernel_launch(void* const* d_in, const int* in_sizes, int n_in,
                              void* d_out, int out_size, void* d_ws, size_t ws_size,
                              hipStream_t stream) {
  const float* H   = (const float*)d_in[0];
  const int*   TYP = (const int*)  d_in[1];
  const float* W0  = (const float*)d_in[2];
  const float* B0v = (const float*)d_in[3];
  const float* W1  = (const float*)d_in[4];
  const float* B1v = (const float*)d_in[5];
  float* OUT = (float*)d_out;

  if (ws_size < WS_NEED) {
    // workspace too small for the sorted path — verified round-4 kernel
    dim3 grid(DDIM / BNd, T_TOK / BMd);
    mot_mfma_diag<<<grid, dim3(256), 0, stream>>>(H, TYP, W0, B0v, W1, B1v, OUT);
    return;
  }

  unsigned short* Hbf  = (unsigned short*)((char*)d_ws + WS_HBF);
  unsigned short* W0bf = (unsigned short*)((char*)d_ws + WS_W0BF);
  unsigned short* W1bf = (unsigned short*)((char*)d_ws + WS_W1BF);
  int* meta = (int*)((char*)d_ws + WS_META);
  int* idx  = (int*)((char*)d_ws + WS_IDX);

  k_convert<<<2048, 256, 0, stream>>>(H,  Hbf,  T_TOK * DDIM / 4);
  k_convert<<<512,  256, 0, stream>>>(W0, W0bf, DDIM * DDIM / 4);
  k_convert<<<512,  256, 0, stream>>>(W1, W1bf, DDIM * DDIM / 4);
  k_init   <<<66,   256, 0, stream>>>(meta, idx, T_TOK + 256);
  k_count  <<<64,   256, 0, stream>>>(TYP, meta);
  k_pad    <<<1,    1,   0, stream>>>(meta);
  k_scatter<<<64,   256, 0, stream>>>(TYP, meta, idx);
  k_gemm<<<MTILE * NTILE, 256, 0, stream>>>(Hbf, W0bf, W1bf, B0v, B1v, meta, idx, OUT);
}

// Round 6
// 250.108 us; speedup vs baseline: 17.3307x; 1.0242x over previous
//
#include <hip/hip_runtime.h>
#include <hip/hip_bf16.h>
#include <stdint.h>

// MoTEmbed: out[t,:] = W_{type(t)} @ h[t,:] + b_{type(t)}
// B=4, S=4096 -> T=16384 tokens, D=2048. fp32 in/out, bf16 MFMA compute.
// Round 6: 256x256 8-phase GEMM (T3+T4 counted vmcnt, T5 setprio), k-half
// LDS layout (64B rows -> conflict-free ds_read_b128, no swizzle needed),
// token-sort by type (single-expert), bf16 pre-convert in d_ws.

#define T_TOK 16384
#define DDIM  2048
#define NT_K  32           // K tiles of 64
#define MT    65           // M tiles of 256 (64 + 1 pad-split)
#define NTILE 8            // N tiles of 256

typedef __attribute__((ext_vector_type(4))) float          f32x4;
typedef __attribute__((ext_vector_type(8))) short          bf16x8;
typedef __attribute__((ext_vector_type(2))) unsigned int   u32x2;

// ---- ws layout (bytes) ----
#define WS_HBF   0ull
#define WS_W0BF  67108864ull                 // 16384*2048*2
#define WS_W1BF  75497472ull                 // + 2048*2048*2
#define WS_META  83886080ull                 // + 2048*2048*2
#define WS_IDX   83886208ull
#define WS_NEED  (WS_IDX + (unsigned long long)(T_TOK + 256) * 4ull)
// meta: [0]=c0 [1]=c0pad(256) [2]=cur0 [3]=cur1

__device__ __forceinline__ unsigned short cvt1_bf16(float f) {
  unsigned u = __builtin_bit_cast(unsigned, f);
  unsigned rnd = 0x7fffu + ((u >> 16) & 1u);
  return (unsigned short)((u + rnd) >> 16);
}

__device__ __forceinline__ void gload_lds16(const void* g, void* l) {
  __builtin_amdgcn_global_load_lds(
      (const __attribute__((address_space(1))) unsigned int*)g,
      (__attribute__((address_space(3))) unsigned int*)l, 16, 0, 0);
}

#define BAR()    asm volatile("s_barrier" ::: "memory")
#define VMCNT(n) asm volatile("s_waitcnt vmcnt(" #n ")" ::: "memory")

// ---------- prep kernels ----------
__global__ void k_convert(const float* __restrict__ src,
                          unsigned short* __restrict__ dst, int n4) {
  int i = blockIdx.x * blockDim.x + threadIdx.x;
  int stride = gridDim.x * blockDim.x;
  for (; i < n4; i += stride) {
    f32x4 v = ((const f32x4*)src)[i];
    unsigned p0 = (unsigned)cvt1_bf16(v[0]) | ((unsigned)cvt1_bf16(v[1]) << 16);
    unsigned p1 = (unsigned)cvt1_bf16(v[2]) | ((unsigned)cvt1_bf16(v[3]) << 16);
    u32x2 o; o[0] = p0; o[1] = p1;
    ((u32x2*)dst)[i] = o;
  }
}

__global__ void k_init(int* __restrict__ meta, int* __restrict__ idx, int n) {
  int i = blockIdx.x * blockDim.x + threadIdx.x;
  if (i < 4) meta[i] = 0;
  if (i < n) idx[i] = -1;
}

__global__ void k_count(const int* __restrict__ typ, int* __restrict__ meta) {
  int i = blockIdx.x * blockDim.x + threadIdx.x;
  if (i < T_TOK && typ[i] == 0) atomicAdd(&meta[0], 1);
}

__global__ void k_pad(int* __restrict__ meta) {
  meta[1] = ((meta[0] + 255) >> 8) << 8;   // pad expert-0 region to 256
}

__global__ void k_scatter(const int* __restrict__ typ, int* __restrict__ meta,
                          int* __restrict__ idx) {
  int i = blockIdx.x * blockDim.x + threadIdx.x;
  if (i >= T_TOK) return;
  int t = typ[i];
  int pos;
  if (t == 0) pos = atomicAdd(&meta[2], 1);
  else        pos = meta[1] + atomicAdd(&meta[3], 1);
  idx[pos] = i;
}

// ---------- 256x256 8-phase GEMM ----------
// LDS: A[2 buf][2 kh][256 rows][64 B] = 64KB, then B same = 64KB.
// Section = 16KB = 16 chunks of 1KB (16 rows x 64B); wave w stages chunks
// {2w, 2w+1} per half-tile (2 global_load_lds per thread per stage).
// vmcnt ledger (2 loads/stage, per-tile stage order Akh0,Bkh0,Akh1,Bkh1):
//   P1 wait vmcnt(4) -> Akh0(t),Bkh0(t) landed; P2 wait vmcnt(2) ->
//   Akh1(t),Bkh1(t) landed; P3/P4 no wait. Never 0 in main loop.
__global__ __launch_bounds__(512, 2) void k_gemm256(
    const unsigned short* __restrict__ Hbf,
    const unsigned short* __restrict__ W0bf,
    const unsigned short* __restrict__ W1bf,
    const float* __restrict__ B0, const float* __restrict__ B1,
    const int* __restrict__ meta, const int* __restrict__ idx,
    float* __restrict__ OUT)
{
  __shared__ char lds[131072];

  // bijective XCD swizzle: nwg=520, 520%8==0, chunk=65
  const int orig = blockIdx.x;
  const int wg = (orig & 7) * 65 + (orig >> 3);
  const int my = wg >> 3;              // 0..64
  const int bx = wg & 7;               // 0..7

  const int tid  = threadIdx.x;
  const int lane = tid & 63;
  const int wid  = tid >> 6;           // 0..7
  const int wr   = wid >> 2;           // 0..1 (M half)
  const int wc   = wid & 3;            // 0..3 (N quarter)
  const int fr   = lane & 15;
  const int g    = lane >> 4;

  const int start  = my * 256;
  const int c0pad  = meta[1];
  const int expert = (start >= c0pad) ? 1 : 0;
  const unsigned short* Wb = expert ? W1bf : W0bf;
  const int colBase = bx * 256;

  // staging sources (A rows gathered via idx; per-lane global addresses)
  const char* aS[2];
  const char* wS[2];
#pragma unroll
  for (int l = 0; l < 2; ++l) {
    int ch = 2 * wid + l;
    int r_tile = ch * 16 + (lane >> 2);
    int orow = idx[start + r_tile];
    if (orow < 0) orow = 0;
    aS[l] = (const char*)Hbf + (size_t)orow * 4096 + (lane & 3) * 16;
    wS[l] = (const char*)(Wb + (size_t)(colBase + r_tile) * DDIM) + (lane & 3) * 16;
  }
  const int chB = (2 * wid) * 1024;    // wave-uniform chunk base in a section

  // fragment byte offsets within a kh-section
  int aF[8], bF[4];
#pragma unroll
  for (int m = 0; m < 8; ++m) aF[m] = ((wr * 128 + m * 16 + fr) << 6) + (g << 4);
#pragma unroll
  for (int n = 0; n < 4; ++n) bF[n] = ((wc * 64 + n * 16 + fr) << 6) + (g << 4);

  f32x4 acc[8][4];
#pragma unroll
  for (int m = 0; m < 8; ++m)
#pragma unroll
    for (int n = 0; n < 4; ++n) acc[m][n] = (f32x4)0.0f;

  auto STAGE_A = [&](int d, int kh, int tn) {
    char* dst = lds + (d << 15) + (kh << 14) + chB;
    int ko = tn * 128 + kh * 64;
    gload_lds16(aS[0] + ko, dst);
    gload_lds16(aS[1] + ko, dst + 1024);
  };
  auto STAGE_B = [&](int d, int kh, int tn) {
    char* dst = lds + 65536 + (d << 15) + (kh << 14) + chB;
    int ko = tn * 128 + kh * 64;
    gload_lds16(wS[0] + ko, dst);
    gload_lds16(wS[1] + ko, dst + 1024);
  };

  // prologue: tile 0 -> buf 0 (order defines the vmcnt census)
  STAGE_A(0, 0, 0); STAGE_B(0, 0, 0); STAGE_A(0, 1, 0); STAGE_B(0, 1, 0);

#pragma unroll 2
  for (int t = 0; t < NT_K; ++t) {
    const int c = t & 1, d = c ^ 1;
    int tn = t + 1; if (tn == NT_K) tn = NT_K - 1;   // clamp keeps census exact
    const char* Ac0 = lds + (c << 15);
    const char* Ac1 = Ac0 + 16384;
    const char* Bc0 = lds + 65536 + (c << 15);
    const char* Bc1 = Bc0 + 16384;

    bf16x8 a0[8], a1[8], b0v, b1v;

    // ---- P1: ks0 x n{0,1} ----
    VMCNT(4);
    BAR();
#pragma unroll
    for (int m = 0; m < 8; ++m) a0[m] = *(const bf16x8*)(Ac0 + aF[m]);
    b0v = *(const bf16x8*)(Bc0 + bF[0]);
    b1v = *(const bf16x8*)(Bc0 + bF[1]);
    STAGE_A(d, 0, tn);
    __builtin_amdgcn_s_setprio(1);
#pragma unroll
    for (int m = 0; m < 8; ++m) {
      acc[m][0] = __builtin_amdgcn_mfma_f32_16x16x32_bf16(a0[m], b0v, acc[m][0], 0, 0, 0);
      acc[m][1] = __builtin_amdgcn_mfma_f32_16x16x32_bf16(a0[m], b1v, acc[m][1], 0, 0, 0);
    }
    __builtin_amdgcn_s_setprio(0);

    // ---- P2: ks1 x n{0,1} ----
    VMCNT(2);
    BAR();
#pragma unroll
    for (int m = 0; m < 8; ++m) a1[m] = *(const bf16x8*)(Ac1 + aF[m]);
    b0v = *(const bf16x8*)(Bc1 + bF[0]);
    b1v = *(const bf16x8*)(Bc1 + bF[1]);
    STAGE_B(d, 0, tn);
    __builtin_amdgcn_s_setprio(1);
#pragma unroll
    for (int m = 0; m < 8; ++m) {
      acc[m][0] = __builtin_amdgcn_mfma_f32_16x16x32_bf16(a1[m], b0v, acc[m][0], 0, 0, 0);
      acc[m][1] = __builtin_amdgcn_mfma_f32_16x16x32_bf16(a1[m], b1v, acc[m][1], 0, 0, 0);
    }
    __builtin_amdgcn_s_setprio(0);

    // ---- P3: ks0 x n{2,3} (A frags reused from P1) ----
    BAR();
    b0v = *(const bf16x8*)(Bc0 + bF[2]);
    b1v = *(const bf16x8*)(Bc0 + bF[3]);
    STAGE_A(d, 1, tn);
    __builtin_amdgcn_s_setprio(1);
#pragma unroll
    for (int m = 0; m < 8; ++m) {
      acc[m][2] = __builtin_amdgcn_mfma_f32_16x16x32_bf16(a0[m], b0v, acc[m][2], 0, 0, 0);
      acc[m][3] = __builtin_amdgcn_mfma_f32_16x16x32_bf16(a0[m], b1v, acc[m][3], 0, 0, 0);
    }
    __builtin_amdgcn_s_setprio(0);

    // ---- P4: ks1 x n{2,3} ----
    BAR();
    b0v = *(const bf16x8*)(Bc1 + bF[2]);
    b1v = *(const bf16x8*)(Bc1 + bF[3]);
    STAGE_B(d, 1, tn);
    __builtin_amdgcn_s_setprio(1);
#pragma unroll
    for (int m = 0; m < 8; ++m) {
      acc[m][2] = __builtin_amdgcn_mfma_f32_16x16x32_bf16(a1[m], b0v, acc[m][2], 0, 0, 0);
      acc[m][3] = __builtin_amdgcn_mfma_f32_16x16x32_bf16(a1[m], b1v, acc[m][3], 0, 0, 0);
    }
    __builtin_amdgcn_s_setprio(0);
  }

  // ---- epilogue: bias + scatter to original rows ----
  const float* Bv = expert ? B1 : B0;
  float bias[4];
  int cols[4];
#pragma unroll
  for (int n = 0; n < 4; ++n) {
    cols[n] = colBase + wc * 64 + n * 16 + fr;
    bias[n] = Bv[cols[n]];
  }
#pragma unroll
  for (int m = 0; m < 8; ++m) {
    int lb = wr * 128 + m * 16 + (g << 2);
#pragma unroll
    for (int j = 0; j < 4; ++j) {
      int orow = idx[start + lb + j];
      if (orow < 0) continue;
      float* op = OUT + (size_t)orow * DDIM;
#pragma unroll
      for (int n = 0; n < 4; ++n) op[cols[n]] = acc[m][n][j] + bias[n];
    }
  }
}

// ---------- fallback: verified round-4 kernel ----------
#define BMd 64
#define BNd 64
#define BKd 32
#define LDW 36

__device__ __forceinline__ bf16x8 cvt_bf16x8(f32x4 lo, f32x4 hi) {
  bf16x8 r;
#pragma unroll
  for (int i = 0; i < 4; ++i) {
    r[i]     = (short)cvt1_bf16(lo[i]);
    r[i + 4] = (short)cvt1_bf16(hi[i]);
  }
  return r;
}

__global__ __launch_bounds__(256, 2) void mot_mfma_diag(
    const float* __restrict__ H,  const int* __restrict__ TYP,
    const float* __restrict__ W0, const float* __restrict__ B0,
    const float* __restrict__ W1, const float* __restrict__ B1,
    float* __restrict__ OUT)
{
  __shared__ float As[BMd * LDW];
  __shared__ float W0s[BNd * LDW];
  __shared__ float W1s[BNd * LDW];

  const int tid = threadIdx.x;
  const int rowBase = blockIdx.y * BMd;
  const int colBase = blockIdx.x * BNd;
  const int srow  = tid >> 3;
  const int scol4 = (tid & 7) << 2;
  const float* hA  = H  + (size_t)(rowBase + srow) * DDIM + scol4;
  const float* hW0 = W0 + (size_t)(colBase + srow) * DDIM + scol4;
  const float* hW1 = W1 + (size_t)(colBase + srow) * DDIM + scol4;

  const int lane = tid & 63;
  const int w    = tid >> 6;
  const int fr   = lane & 15;
  const int g    = lane >> 4;

  f32x4 acc0[4], acc1[4];
#pragma unroll
  for (int m = 0; m < 4; ++m) { acc0[m] = (f32x4)0.0f; acc1[m] = (f32x4)0.0f; }

  for (int k0 = 0; k0 < DDIM; k0 += BKd) {
    f32x4 va[2], v0[2], v1[2];
#pragma unroll
    for (int p = 0; p < 2; ++p) {
      va[p] = *(const f32x4*)(hA  + (size_t)p * 32 * DDIM);
      v0[p] = *(const f32x4*)(hW0 + (size_t)p * 32 * DDIM);
      v1[p] = *(const f32x4*)(hW1 + (size_t)p * 32 * DDIM);
    }
    hA += BKd; hW0 += BKd; hW1 += BKd;
    __syncthreads();
#pragma unroll
    for (int p = 0; p < 2; ++p) {
      int r = srow + 32 * p;
      *(f32x4*)(&As [r * LDW + scol4]) = va[p];
      *(f32x4*)(&W0s[r * LDW + scol4]) = v0[p];
      *(f32x4*)(&W1s[r * LDW + scol4]) = v1[p];
    }
    __syncthreads();

    bf16x8 af[4];
#pragma unroll
    for (int m = 0; m < 4; ++m) {
      const float* ap = &As[(m * 16 + fr) * LDW + g * 8];
      af[m] = cvt_bf16x8(*(const f32x4*)ap, *(const f32x4*)(ap + 4));
    }
    const float* b0p = &W0s[(w * 16 + fr) * LDW + g * 8];
    const float* b1p = &W1s[(w * 16 + fr) * LDW + g * 8];
    bf16x8 bf0 = cvt_bf16x8(*(const f32x4*)b0p, *(const f32x4*)(b0p + 4));
    bf16x8 bf1 = cvt_bf16x8(*(const f32x4*)b1p, *(const f32x4*)(b1p + 4));
#pragma unroll
    for (int m = 0; m < 4; ++m) {
      acc0[m] = __builtin_amdgcn_mfma_f32_16x16x32_bf16(af[m], bf0, acc0[m], 0, 0, 0);
      acc1[m] = __builtin_amdgcn_mfma_f32_16x16x32_bf16(af[m], bf1, acc1[m], 0, 0, 0);
    }
  }

  const int col = colBase + w * 16 + fr;
  const float bz0 = B0[col];
  const float bz1 = B1[col];
#pragma unroll
  for (int m = 0; m < 4; ++m)
#pragma unroll
    for (int j = 0; j < 4; ++j) {
      int row = rowBase + m * 16 + (g << 2) + j;
      int t = TYP[row];
      OUT[(size_t)row * DDIM + col] = (t == 0) ? (acc0[m][j] + bz0) : (acc1[m][j] + bz1);
    }
}

extern "C" void kernel_launch(void* const* d_in, const int* in_sizes, int n_in,
                              void* d_out, int out_size, void* d_ws, size_t ws_size,
                              hipStream_t stream) {
  const float* H   = (const float*)d_in[0];
  const int*   TYP = (const int*)  d_in[1];
  const float* W0  = (const float*)d_in[2];
  const float* B0v = (const float*)d_in[3];
  const float* W1  = (const float*)d_in[4];
  const float* B1v = (const float*)d_in[5];
  float* OUT = (float*)d_out;

  if (ws_size < WS_NEED) {
    dim3 grid(DDIM / BNd, T_TOK / BMd);
    mot_mfma_diag<<<grid, dim3(256), 0, stream>>>(H, TYP, W0, B0v, W1, B1v, OUT);
    return;
  }

  unsigned short* Hbf  = (unsigned short*)((char*)d_ws + WS_HBF);
  unsigned short* W0bf = (unsigned short*)((char*)d_ws + WS_W0BF);
  unsigned short* W1bf = (unsigned short*)((char*)d_ws + WS_W1BF);
  int* meta = (int*)((char*)d_ws + WS_META);
  int* idx  = (int*)((char*)d_ws + WS_IDX);

  k_convert<<<2048, 256, 0, stream>>>(H,  Hbf,  T_TOK * DDIM / 4);
  k_convert<<<512,  256, 0, stream>>>(W0, W0bf, DDIM * DDIM / 4);
  k_convert<<<512,  256, 0, stream>>>(W1, W1bf, DDIM * DDIM / 4);
  k_init   <<<66,   256, 0, stream>>>(meta, idx, T_TOK + 256);
  k_count  <<<64,   256, 0, stream>>>(TYP, meta);
  k_pad    <<<1,    1,   0, stream>>>(meta);
  k_scatter<<<64,   256, 0, stream>>>(TYP, meta, idx);
  k_gemm256<<<MT * NTILE, 512, 0, stream>>>(Hbf, W0bf, W1bf, B0v, B1v, meta, idx, OUT);
}

// Round 7
// 245.100 us; speedup vs baseline: 17.6849x; 1.0204x over previous
//
#include <hip/hip_runtime.h>
#include <hip/hip_bf16.h>
#include <stdint.h>

// MoTEmbed: out[t,:] = W_{type(t)} @ h[t,:] + b_{type(t)}
// B=4, S=4096 -> T=16384 tokens, D=2048. fp32 in/out, bf16 MFMA compute.
// Round 7: + XOR bank swizzle (2-way = free) on both write-source and read
// sides (rule 21), m201-template phase cadence (reads pre-barrier, double
// barrier, vmcnt(4) at P2/P4 pre-barrier, lgkmcnt(0), setprio).

#define T_TOK 16384
#define DDIM  2048
#define NT_K  32           // K tiles of 64
#define MT    65           // M tiles of 256 (64 + 1 pad-split)
#define NTILE 8            // N tiles of 256

typedef __attribute__((ext_vector_type(4))) float          f32x4;
typedef __attribute__((ext_vector_type(8))) short          bf16x8;
typedef __attribute__((ext_vector_type(2))) unsigned int   u32x2;

// ---- ws layout (bytes) ----
#define WS_HBF   0ull
#define WS_W0BF  67108864ull                 // 16384*2048*2
#define WS_W1BF  75497472ull                 // + 2048*2048*2
#define WS_META  83886080ull                 // + 2048*2048*2
#define WS_IDX   83886208ull
#define WS_NEED  (WS_IDX + (unsigned long long)(T_TOK + 256) * 4ull)
// meta: [0]=c0 [1]=c0pad(256) [2]=cur0 [3]=cur1

__device__ __forceinline__ unsigned short cvt1_bf16(float f) {
  unsigned u = __builtin_bit_cast(unsigned, f);
  unsigned rnd = 0x7fffu + ((u >> 16) & 1u);
  return (unsigned short)((u + rnd) >> 16);
}

__device__ __forceinline__ void gload_lds16(const void* g, void* l) {
  __builtin_amdgcn_global_load_lds(
      (const __attribute__((address_space(1))) unsigned int*)g,
      (__attribute__((address_space(3))) unsigned int*)l, 16, 0, 0);
}

#define BAR()    asm volatile("s_barrier" ::: "memory")
#define VMCNT4() asm volatile("s_waitcnt vmcnt(4)" ::: "memory")
#define LGKM0()  asm volatile("s_waitcnt lgkmcnt(0)" ::: "memory")

// ---------- prep kernels ----------
__global__ void k_convert(const float* __restrict__ src,
                          unsigned short* __restrict__ dst, int n4) {
  int i = blockIdx.x * blockDim.x + threadIdx.x;
  int stride = gridDim.x * blockDim.x;
  for (; i < n4; i += stride) {
    f32x4 v = ((const f32x4*)src)[i];
    unsigned p0 = (unsigned)cvt1_bf16(v[0]) | ((unsigned)cvt1_bf16(v[1]) << 16);
    unsigned p1 = (unsigned)cvt1_bf16(v[2]) | ((unsigned)cvt1_bf16(v[3]) << 16);
    u32x2 o; o[0] = p0; o[1] = p1;
    ((u32x2*)dst)[i] = o;
  }
}

__global__ void k_init(int* __restrict__ meta, int* __restrict__ idx, int n) {
  int i = blockIdx.x * blockDim.x + threadIdx.x;
  if (i < 4) meta[i] = 0;
  if (i < n) idx[i] = -1;
}

__global__ void k_count(const int* __restrict__ typ, int* __restrict__ meta) {
  int i = blockIdx.x * blockDim.x + threadIdx.x;
  if (i < T_TOK && typ[i] == 0) atomicAdd(&meta[0], 1);
}

__global__ void k_pad(int* __restrict__ meta) {
  meta[1] = ((meta[0] + 255) >> 8) << 8;   // pad expert-0 region to 256
}

__global__ void k_scatter(const int* __restrict__ typ, int* __restrict__ meta,
                          int* __restrict__ idx) {
  int i = blockIdx.x * blockDim.x + threadIdx.x;
  if (i >= T_TOK) return;
  int t = typ[i];
  int pos;
  if (t == 0) pos = atomicAdd(&meta[2], 1);
  else        pos = meta[1] + atomicAdd(&meta[3], 1);
  idx[pos] = i;
}

// ---------- 256x256 8-phase GEMM, swizzled LDS ----------
// LDS: A[2 buf][2 kh][256 rows][64 B] = 64KB, then B same = 64KB.
// Swizzle: data (row, slot s) stored at LDS slot s ^ ((row>>1)&3).
//   write: linear LDS dest (global_load_lds), global source slot
//          cs = (lane&3) ^ ((lane>>3)&3)   (lane>>2 = row-in-chunk)
//   read : slot = g ^ ((fr>>1)&3)  -> 2 lanes per bank-quad = free (m136).
// vmcnt ledger (loads, 2/stage, order A0,B0,A1,B1 per tile):
//   prologue 8 loads, vmcnt(4) -> kh0 landed.  P2: +stage, vmcnt(4)
//   drains prev kh1 (consumed P3).  P4: +stage, vmcnt(4) drains this
//   tile's kh0 (consumed next P1).  Every drain precedes a barrier that
//   precedes its consumers; never vmcnt(0); max 8 outstanding.
__global__ __launch_bounds__(512, 2) void k_gemm256(
    const unsigned short* __restrict__ Hbf,
    const unsigned short* __restrict__ W0bf,
    const unsigned short* __restrict__ W1bf,
    const float* __restrict__ B0, const float* __restrict__ B1,
    const int* __restrict__ meta, const int* __restrict__ idx,
    float* __restrict__ OUT)
{
  __shared__ char lds[131072];

  // bijective XCD swizzle: nwg=520, 520%8==0, chunk=65
  const int orig = blockIdx.x;
  const int wg = (orig & 7) * 65 + (orig >> 3);
  const int my = wg >> 3;              // 0..64
  const int bx = wg & 7;               // 0..7

  const int tid  = threadIdx.x;
  const int lane = tid & 63;
  const int wid  = tid >> 6;           // 0..7
  const int wr   = wid >> 2;           // 0..1 (M half)
  const int wc   = wid & 3;            // 0..3 (N quarter)
  const int fr   = lane & 15;
  const int g    = lane >> 4;

  const int start  = my * 256;
  const int c0pad  = meta[1];
  const int expert = (start >= c0pad) ? 1 : 0;
  const unsigned short* Wb = expert ? W1bf : W0bf;
  const int colBase = bx * 256;

  // staging sources; pre-swizzled global slot (rule 21: linear LDS dest)
  const int cs = (lane & 3) ^ ((lane >> 3) & 3);
  const char* aS[2];
  const char* wS[2];
#pragma unroll
  for (int l = 0; l < 2; ++l) {
    int ch = 2 * wid + l;
    int r_tile = ch * 16 + (lane >> 2);
    int orow = idx[start + r_tile];
    if (orow < 0) orow = 0;
    aS[l] = (const char*)Hbf + (size_t)orow * 4096 + cs * 16;
    wS[l] = (const char*)(Wb + (size_t)(colBase + r_tile) * DDIM) + cs * 16;
  }
  const int chB = (2 * wid) * 1024;    // wave-uniform chunk base in a section

  // fragment byte offsets within a kh-section (swizzled slot)
  const int sw = (g ^ ((fr >> 1) & 3)) << 4;
  int aF[8], bF[4];
#pragma unroll
  for (int m = 0; m < 8; ++m) aF[m] = ((wr * 128 + m * 16 + fr) << 6) + sw;
#pragma unroll
  for (int n = 0; n < 4; ++n) bF[n] = ((wc * 64 + n * 16 + fr) << 6) + sw;

  f32x4 acc[8][4];
#pragma unroll
  for (int m = 0; m < 8; ++m)
#pragma unroll
    for (int n = 0; n < 4; ++n) acc[m][n] = (f32x4)0.0f;

  auto STAGE_A = [&](int d, int kh, int tn) {
    char* dst = lds + (d << 15) + (kh << 14) + chB;
    int ko = tn * 128 + kh * 64;
    gload_lds16(aS[0] + ko, dst);
    gload_lds16(aS[1] + ko, dst + 1024);
  };
  auto STAGE_B = [&](int d, int kh, int tn) {
    char* dst = lds + 65536 + (d << 15) + (kh << 14) + chB;
    int ko = tn * 128 + kh * 64;
    gload_lds16(wS[0] + ko, dst);
    gload_lds16(wS[1] + ko, dst + 1024);
  };

  // prologue: tile 0 -> buf 0; kh0 guaranteed landed at barrier
  STAGE_A(0, 0, 0); STAGE_B(0, 0, 0); STAGE_A(0, 1, 0); STAGE_B(0, 1, 0);
  VMCNT4();
  BAR();

#pragma unroll 2
  for (int t = 0; t < NT_K; ++t) {
    const int c = t & 1, d = c ^ 1;
    int tn = t + 1; if (tn == NT_K) tn = NT_K - 1;   // clamp keeps census exact
    const char* Ak0 = lds + (c << 15);
    const char* Ak1 = Ak0 + 16384;
    const char* Bk0 = lds + 65536 + (c << 15);
    const char* Bk1 = Bk0 + 16384;

    bf16x8 a[8], b0v, b1v, b2v, b3v;

    // ---- P1: kh0 x n{0,1} ----
#pragma unroll
    for (int m = 0; m < 8; ++m) a[m] = *(const bf16x8*)(Ak0 + aF[m]);
    b0v = *(const bf16x8*)(Bk0 + bF[0]);
    b1v = *(const bf16x8*)(Bk0 + bF[1]);
    STAGE_A(d, 0, tn);
    BAR(); LGKM0();
    __builtin_amdgcn_s_setprio(1);
#pragma unroll
    for (int m = 0; m < 8; ++m) {
      acc[m][0] = __builtin_amdgcn_mfma_f32_16x16x32_bf16(a[m], b0v, acc[m][0], 0, 0, 0);
      acc[m][1] = __builtin_amdgcn_mfma_f32_16x16x32_bf16(a[m], b1v, acc[m][1], 0, 0, 0);
    }
    __builtin_amdgcn_s_setprio(0);
    BAR();

    // ---- P2: kh0 x n{2,3} (a reused) ----
    b2v = *(const bf16x8*)(Bk0 + bF[2]);
    b3v = *(const bf16x8*)(Bk0 + bF[3]);
    STAGE_B(d, 0, tn);
    VMCNT4();                          // drains prev-tile kh1 stages (P3 reads them)
    BAR(); LGKM0();
    __builtin_amdgcn_s_setprio(1);
#pragma unroll
    for (int m = 0; m < 8; ++m) {
      acc[m][2] = __builtin_amdgcn_mfma_f32_16x16x32_bf16(a[m], b2v, acc[m][2], 0, 0, 0);
      acc[m][3] = __builtin_amdgcn_mfma_f32_16x16x32_bf16(a[m], b3v, acc[m][3], 0, 0, 0);
    }
    __builtin_amdgcn_s_setprio(0);
    BAR();

    // ---- P3: kh1 x n{0,1} ----
#pragma unroll
    for (int m = 0; m < 8; ++m) a[m] = *(const bf16x8*)(Ak1 + aF[m]);
    b0v = *(const bf16x8*)(Bk1 + bF[0]);
    b1v = *(const bf16x8*)(Bk1 + bF[1]);
    STAGE_A(d, 1, tn);
    BAR(); LGKM0();
    __builtin_amdgcn_s_setprio(1);
#pragma unroll
    for (int m = 0; m < 8; ++m) {
      acc[m][0] = __builtin_amdgcn_mfma_f32_16x16x32_bf16(a[m], b0v, acc[m][0], 0, 0, 0);
      acc[m][1] = __builtin_amdgcn_mfma_f32_16x16x32_bf16(a[m], b1v, acc[m][1], 0, 0, 0);
    }
    __builtin_amdgcn_s_setprio(0);
    BAR();

    // ---- P4: kh1 x n{2,3} ----
    b2v = *(const bf16x8*)(Bk1 + bF[2]);
    b3v = *(const bf16x8*)(Bk1 + bF[3]);
    STAGE_B(d, 1, tn);
    VMCNT4();                          // drains this tile's kh0 stages (next P1 reads)
    BAR(); LGKM0();
    __builtin_amdgcn_s_setprio(1);
#pragma unroll
    for (int m = 0; m < 8; ++m) {
      acc[m][2] = __builtin_amdgcn_mfma_f32_16x16x32_bf16(a[m], b2v, acc[m][2], 0, 0, 0);
      acc[m][3] = __builtin_amdgcn_mfma_f32_16x16x32_bf16(a[m], b3v, acc[m][3], 0, 0, 0);
    }
    __builtin_amdgcn_s_setprio(0);
    BAR();
  }

  // ---- epilogue: bias + scatter to original rows ----
  const float* Bv = expert ? B1 : B0;
  float bias[4];
  int cols[4];
#pragma unroll
  for (int n = 0; n < 4; ++n) {
    cols[n] = colBase + wc * 64 + n * 16 + fr;
    bias[n] = Bv[cols[n]];
  }
#pragma unroll
  for (int m = 0; m < 8; ++m) {
    int lb = wr * 128 + m * 16 + (g << 2);
#pragma unroll
    for (int j = 0; j < 4; ++j) {
      int orow = idx[start + lb + j];
      if (orow < 0) continue;
      float* op = OUT + (size_t)orow * DDIM;
#pragma unroll
      for (int n = 0; n < 4; ++n) op[cols[n]] = acc[m][n][j] + bias[n];
    }
  }
}

// ---------- fallback: verified round-4 kernel ----------
#define BMd 64
#define BNd 64
#define BKd 32
#define LDW 36

__device__ __forceinline__ bf16x8 cvt_bf16x8(f32x4 lo, f32x4 hi) {
  bf16x8 r;
#pragma unroll
  for (int i = 0; i < 4; ++i) {
    r[i]     = (short)cvt1_bf16(lo[i]);
    r[i + 4] = (short)cvt1_bf16(hi[i]);
  }
  return r;
}

__global__ __launch_bounds__(256, 2) void mot_mfma_diag(
    const float* __restrict__ H,  const int* __restrict__ TYP,
    const float* __restrict__ W0, const float* __restrict__ B0,
    const float* __restrict__ W1, const float* __restrict__ B1,
    float* __restrict__ OUT)
{
  __shared__ float As[BMd * LDW];
  __shared__ float W0s[BNd * LDW];
  __shared__ float W1s[BNd * LDW];

  const int tid = threadIdx.x;
  const int rowBase = blockIdx.y * BMd;
  const int colBase = blockIdx.x * BNd;
  const int srow  = tid >> 3;
  const int scol4 = (tid & 7) << 2;
  const float* hA  = H  + (size_t)(rowBase + srow) * DDIM + scol4;
  const float* hW0 = W0 + (size_t)(colBase + srow) * DDIM + scol4;
  const float* hW1 = W1 + (size_t)(colBase + srow) * DDIM + scol4;

  const int lane = tid & 63;
  const int w    = tid >> 6;
  const int fr   = lane & 15;
  const int g    = lane >> 4;

  f32x4 acc0[4], acc1[4];
#pragma unroll
  for (int m = 0; m < 4; ++m) { acc0[m] = (f32x4)0.0f; acc1[m] = (f32x4)0.0f; }

  for (int k0 = 0; k0 < DDIM; k0 += BKd) {
    f32x4 va[2], v0[2], v1[2];
#pragma unroll
    for (int p = 0; p < 2; ++p) {
      va[p] = *(const f32x4*)(hA  + (size_t)p * 32 * DDIM);
      v0[p] = *(const f32x4*)(hW0 + (size_t)p * 32 * DDIM);
      v1[p] = *(const f32x4*)(hW1 + (size_t)p * 32 * DDIM);
    }
    hA += BKd; hW0 += BKd; hW1 += BKd;
    __syncthreads();
#pragma unroll
    for (int p = 0; p < 2; ++p) {
      int r = srow + 32 * p;
      *(f32x4*)(&As [r * LDW + scol4]) = va[p];
      *(f32x4*)(&W0s[r * LDW + scol4]) = v0[p];
      *(f32x4*)(&W1s[r * LDW + scol4]) = v1[p];
    }
    __syncthreads();

    bf16x8 af[4];
#pragma unroll
    for (int m = 0; m < 4; ++m) {
      const float* ap = &As[(m * 16 + fr) * LDW + g * 8];
      af[m] = cvt_bf16x8(*(const f32x4*)ap, *(const f32x4*)(ap + 4));
    }
    const float* b0p = &W0s[(w * 16 + fr) * LDW + g * 8];
    const float* b1p = &W1s[(w * 16 + fr) * LDW + g * 8];
    bf16x8 bf0 = cvt_bf16x8(*(const f32x4*)b0p, *(const f32x4*)(b0p + 4));
    bf16x8 bf1 = cvt_bf16x8(*(const f32x4*)b1p, *(const f32x4*)(b1p + 4));
#pragma unroll
    for (int m = 0; m < 4; ++m) {
      acc0[m] = __builtin_amdgcn_mfma_f32_16x16x32_bf16(af[m], bf0, acc0[m], 0, 0, 0);
      acc1[m] = __builtin_amdgcn_mfma_f32_16x16x32_bf16(af[m], bf1, acc1[m], 0, 0, 0);
    }
  }

  const int col = colBase + w * 16 + fr;
  const float bz0 = B0[col];
  const float bz1 = B1[col];
#pragma unroll
  for (int m = 0; m < 4; ++m)
#pragma unroll
    for (int j = 0; j < 4; ++j) {
      int row = rowBase + m * 16 + (g << 2) + j;
      int t = TYP[row];
      OUT[(size_t)row * DDIM + col] = (t == 0) ? (acc0[m][j] + bz0) : (acc1[m][j] + bz1);
    }
}

extern "C" void kernel_launch(void* const* d_in, const int* in_sizes, int n_in,
                              void* d_out, int out_size, void* d_ws, size_t ws_size,
                              hipStream_t stream) {
  const float* H   = (const float*)d_in[0];
  const int*   TYP = (const int*)  d_in[1];
  const float* W0  = (const float*)d_in[2];
  const float* B0v = (const float*)d_in[3];
  const float* W1  = (const float*)d_in[4];
  const float* B1v = (const float*)d_in[5];
  float* OUT = (float*)d_out;

  if (ws_size < WS_NEED) {
    dim3 grid(DDIM / BNd, T_TOK / BMd);
    mot_mfma_diag<<<grid, dim3(256), 0, stream>>>(H, TYP, W0, B0v, W1, B1v, OUT);
    return;
  }

  unsigned short* Hbf  = (unsigned short*)((char*)d_ws + WS_HBF);
  unsigned short* W0bf = (unsigned short*)((char*)d_ws + WS_W0BF);
  unsigned short* W1bf = (unsigned short*)((char*)d_ws + WS_W1BF);
  int* meta = (int*)((char*)d_ws + WS_META);
  int* idx  = (int*)((char*)d_ws + WS_IDX);

  k_convert<<<2048, 256, 0, stream>>>(H,  Hbf,  T_TOK * DDIM / 4);
  k_convert<<<512,  256, 0, stream>>>(W0, W0bf, DDIM * DDIM / 4);
  k_convert<<<512,  256, 0, stream>>>(W1, W1bf, DDIM * DDIM / 4);
  k_init   <<<66,   256, 0, stream>>>(meta, idx, T_TOK + 256);
  k_count  <<<64,   256, 0, stream>>>(TYP, meta);
  k_pad    <<<1,    1,   0, stream>>>(meta);
  k_scatter<<<64,   256, 0, stream>>>(TYP, meta, idx);
  k_gemm256<<<MT * NTILE, 512, 0, stream>>>(Hbf, W0bf, W1bf, B0v, B1v, meta, idx, OUT);
}